// Round 13
// baseline (231.776 us; speedup 1.0000x reference)
//
#include <hip/hip_runtime.h>
#include <hip/hip_bf16.h>

// DifferentiableRenderer R13 = R12 resubmitted (infra timeout; never measured).
// R11 measured (58.5 us, absmax 0.0): spill fixed (FETCH 80MB->1.2MB,
// VGPR 60) but 125 KB LDS forced 1 block/CU -> 512 blocks = 2 serial
// rounds at 4 waves/EU (Occupancy 37%, VALUBusy 35% -> stall-bound on
// barriers + scatter-load latency). Fix: slab depth 5 -> 64000 B dynamic
// LDS -> 2 blocks/CU (128 KB, 2048 thr = CU limits) -> all 512 blocks
// co-resident, 8 waves/EU. Init traffic is NP*CELLS*8B = 512 KB/block
// regardless of DEPTH; only the predicate replay doubles (8x32 unpacks).
// Pin waves_per_eu(8,8): budget 64 VGPR, measured need 60.
//
// Structure: scatter VALUES (float2 sigmoid(a),sigmoid(t)) into a z-major
// LDS slab; 8 passes of depth-5 slabs. Dest cells cached u16-packed in
// cpk[16]; pre[v] loaded lazily under the slab-range predicate (each voxel
// belongs to exactly one slab -> 32 loads/thread/kernel, L2-resident).
// Empty cell = (0,0) -> exact no-op (sigmoid(-1e9) == 0 in fp32).
//
// Numerics unchanged (absmax 0.0 in R2-R5, R11): transform
// c = fmaf(z,R2c, fmaf(y,R1c, x*R0c)) + 20, clip [0,39], trunc;
// march S = fmaf(T*t, a, S), T *= (1-t); sigmoids = 1/(1+expf(-x)).

#define NBATCH 512
#define G      40
#define NRAYS  (G*G)       // 1600
#define NVOX   32768
#define DEPTH  5
#define CELLS  (DEPTH*NRAYS)   // 8000 cells = 64000 B
#define NP     (G/DEPTH)       // 8 passes

// ---------- prep: per-voxel sigmoid table ----------
__global__ __launch_bounds__(256)
void prep_kernel(const float* __restrict__ ab, const float* __restrict__ at,
                 float2* __restrict__ pre)
{
    const int i = blockIdx.x * 256 + threadIdx.x;
    if (i < NVOX)
        pre[i] = make_float2(1.f / (1.f + expf(-ab[i])),
                             1.f / (1.f + expf(-at[i])));
}

// ---------- render: value slab in LDS, 8 z-passes, 2 blocks/CU ----------
template<bool USE_PRE>
__global__ __launch_bounds__(1024)
__attribute__((amdgpu_waves_per_eu(8, 8)))   // 2 blocks/CU = 8 waves/EU; VGPR budget 64 (need ~60)
void render_kernel(const float* __restrict__ Rall,
                   const float2* __restrict__ pre,
                   const float* __restrict__ ab,
                   const float* __restrict__ at,
                   float* __restrict__ out)
{
    extern __shared__ float2 grid[];       // [DEPTH][NRAYS] z-major, 64000 B

    const int b   = blockIdx.x;
    const int tid = threadIdx.x;

    const float* R = Rall + b * 9;
    const float r00 = R[0], r01 = R[1], r02 = R[2];
    const float r10 = R[3], r11 = R[4], r12 = R[5];
    const float r20 = R[6], r21 = R[7], r22 = R[8];

    // v = tid + it*1024  =>  i = it, j = (tid>>5)&31, k = tid&31
    const float y = (float)((tid >> 5) & 31) - 16.f;
    const float z = (float)(tid & 31) - 16.f;

    // --- cache destination cells only (u16-packed, 16 VGPR) ---
    unsigned cpk[16];
    #pragma unroll
    for (int it = 0; it < 32; ++it) {
        const float x = (float)it - 16.f;
        const float c0 = fmaf(z, r20, fmaf(y, r10, x * r00)) + 20.f;
        const float c1 = fmaf(z, r21, fmaf(y, r11, x * r01)) + 20.f;
        const float c2 = fmaf(z, r22, fmaf(y, r12, x * r02)) + 20.f;
        const int i0 = (int)fminf(fmaxf(c0, 0.f), 39.f);
        const int i1 = (int)fminf(fmaxf(c1, 0.f), 39.f);
        const int i2 = (int)fminf(fmaxf(c2, 0.f), 39.f);
        const unsigned cell = (unsigned)(i2 * NRAYS + i0 * G + i1); // < 64000, fits u16
        if (it & 1) cpk[it >> 1] |= cell << 16;
        else        cpk[it >> 1]  = cell;
    }

    const int  ray1 = tid + 1024;
    const bool has1 = (ray1 < NRAYS);   // tid < 576, wave-uniform (576 = 9*64)
    float S0 = 0.f, T0 = 1.f, S1 = 0.f, T1 = 1.f;

    for (int p = 0; p < NP; ++p) {
        const unsigned lo = (unsigned)(p * CELLS);

        // --- init slab to (0,0): 4000 uint4 stores ---
        uint4* g4 = (uint4*)grid;
        const uint4 z4 = make_uint4(0u, 0u, 0u, 0u);
        for (int c = tid; c < CELLS / 2; c += 1024)
            g4[c] = z4;
        __syncthreads();

        // --- scatter: lazy predicated value load (each voxel hits ONE pass) ---
        #pragma unroll
        for (int it = 0; it < 32; ++it) {
            const unsigned cell = (cpk[it >> 1] >> ((it & 1) << 4)) & 0xFFFFu;
            const unsigned rel  = cell - lo;       // wraps if below lo
            if (rel < (unsigned)CELLS) {
                const int v = tid + (it << 10);
                if (USE_PRE) {
                    grid[rel] = pre[v];            // L2-resident 8B load
                } else {
                    grid[rel] = make_float2(1.f / (1.f + expf(-ab[v])),
                                            1.f / (1.f + expf(-at[v])));
                }
                // dup cells: racy 8B write = unspecified winner (JAX set)
            }
        }
        __syncthreads();

        // --- march slab: rays tid and tid+1024 ---
        #pragma unroll
        for (int zl = 0; zl < DEPTH; ++zl) {
            const int base = zl * NRAYS;
            const float2 p0 = grid[base + tid];
            S0 = fmaf(T0 * p0.y, p0.x, S0);
            T0 *= (1.f - p0.y);
            if (has1) {
                const float2 p1 = grid[base + ray1];
                S1 = fmaf(T1 * p1.y, p1.x, S1);
                T1 *= (1.f - p1.y);
            }
        }
        __syncthreads();   // protect slab before next pass's init
    }

    out[b * NRAYS + tid] = S0;
    if (has1) out[b * NRAYS + ray1] = S1;
}

extern "C" void kernel_launch(void* const* d_in, const int* in_sizes, int n_in,
                              void* d_out, int out_size, void* d_ws, size_t ws_size,
                              hipStream_t stream)
{
    const float* Rall = (const float*)d_in[0];   // [512,3,3]
    const float* ab   = (const float*)d_in[1];   // [32,32,32,1]
    const float* at   = (const float*)d_in[2];   // [32,32,32,1]
    float*       out  = (float*)d_out;           // [512,40,40,1]
    float2*      pre  = (float2*)d_ws;

    const bool use_pre = ws_size >= (size_t)NVOX * sizeof(float2);

    if (use_pre) {
        prep_kernel<<<(NVOX + 255) / 256, 256, 0, stream>>>(ab, at, pre);
        render_kernel<true ><<<NBATCH, 1024, CELLS * 8, stream>>>(Rall, pre, ab, at, out);
    } else {
        render_kernel<false><<<NBATCH, 1024, CELLS * 8, stream>>>(Rall, pre, ab, at, out);
    }
}

// Round 14
// 145.106 us; speedup vs baseline: 1.5973x; 1.5973x over previous
//
#include <hip/hip_runtime.h>
#include <hip/hip_bf16.h>

// DifferentiableRenderer R14: DEPTH=5, NO waves_per_eu attribute.
// Ledger: R11 (DEPTH=10, pin(4,4), lazy-load): VGPR 60, no spill, 58.5 us,
// but 1 block/CU -> 2 serial rounds. R13 (DEPTH=5, pin(8,8)): allocator
// compiled to a 32-VGPR cap (!) and spilled everything -> 175 us, FETCH
// 238 MB. The waves_per_eu attribute is unpredictable on gfx950 -> drop it.
// Unpinned heuristic (known from R4/R5) caps at 64 VGPR targeting 8
// waves/EU = exactly DEPTH=5's geometry (2 blocks/CU x 16 waves), and the
// lazy-load structure needs only ~60 VGPR -> fits, no spill expected.
//
// Structure: scatter VALUES (float2 sigmoid(a),sigmoid(t)) into a z-major
// LDS slab; 8 passes of depth-5 slabs (64000 B dynamic LDS, 2 blocks/CU,
// all 512 blocks co-resident in one round). Dest cells cached u16-packed
// in cpk[16]; pre[v] loaded lazily under the slab-range predicate (each
// voxel belongs to exactly one slab -> 32 loads/thread/kernel, L2-resident,
// coalesced). Empty cell = (0,0) -> exact no-op (sigmoid(-1e9)==0 in fp32).
//
// Numerics unchanged (absmax 0.0 in R2-R5, R11, R13): transform
// c = fmaf(z,R2c, fmaf(y,R1c, x*R0c)) + 20, clip [0,39], trunc;
// march S = fmaf(T*t, a, S), T *= (1-t); sigmoids = 1/(1+expf(-x)).

#define NBATCH 512
#define G      40
#define NRAYS  (G*G)       // 1600
#define NVOX   32768
#define DEPTH  5
#define CELLS  (DEPTH*NRAYS)   // 8000 cells = 64000 B
#define NP     (G/DEPTH)       // 8 passes

// ---------- prep: per-voxel sigmoid table ----------
__global__ __launch_bounds__(256)
void prep_kernel(const float* __restrict__ ab, const float* __restrict__ at,
                 float2* __restrict__ pre)
{
    const int i = blockIdx.x * 256 + threadIdx.x;
    if (i < NVOX)
        pre[i] = make_float2(1.f / (1.f + expf(-ab[i])),
                             1.f / (1.f + expf(-at[i])));
}

// ---------- render: value slab in LDS, 8 z-passes, 2 blocks/CU ----------
template<bool USE_PRE>
__global__ __launch_bounds__(1024)   // unpinned: heuristic 64-VGPR cap = 8 waves/EU,
                                     // matches 2-block/CU geometry; need ~60 -> fits
void render_kernel(const float* __restrict__ Rall,
                   const float2* __restrict__ pre,
                   const float* __restrict__ ab,
                   const float* __restrict__ at,
                   float* __restrict__ out)
{
    extern __shared__ float2 grid[];       // [DEPTH][NRAYS] z-major, 64000 B

    const int b   = blockIdx.x;
    const int tid = threadIdx.x;

    const float* R = Rall + b * 9;
    const float r00 = R[0], r01 = R[1], r02 = R[2];
    const float r10 = R[3], r11 = R[4], r12 = R[5];
    const float r20 = R[6], r21 = R[7], r22 = R[8];

    // v = tid + it*1024  =>  i = it, j = (tid>>5)&31, k = tid&31
    const float y = (float)((tid >> 5) & 31) - 16.f;
    const float z = (float)(tid & 31) - 16.f;

    // --- cache destination cells only (u16-packed, 16 VGPR) ---
    unsigned cpk[16];
    #pragma unroll
    for (int it = 0; it < 32; ++it) {
        const float x = (float)it - 16.f;
        const float c0 = fmaf(z, r20, fmaf(y, r10, x * r00)) + 20.f;
        const float c1 = fmaf(z, r21, fmaf(y, r11, x * r01)) + 20.f;
        const float c2 = fmaf(z, r22, fmaf(y, r12, x * r02)) + 20.f;
        const int i0 = (int)fminf(fmaxf(c0, 0.f), 39.f);
        const int i1 = (int)fminf(fmaxf(c1, 0.f), 39.f);
        const int i2 = (int)fminf(fmaxf(c2, 0.f), 39.f);
        const unsigned cell = (unsigned)(i2 * NRAYS + i0 * G + i1); // < 64000, fits u16
        if (it & 1) cpk[it >> 1] |= cell << 16;
        else        cpk[it >> 1]  = cell;
    }

    const int  ray1 = tid + 1024;
    const bool has1 = (ray1 < NRAYS);   // tid < 576, wave-uniform (576 = 9*64)
    float S0 = 0.f, T0 = 1.f, S1 = 0.f, T1 = 1.f;

    for (int p = 0; p < NP; ++p) {
        const unsigned lo = (unsigned)(p * CELLS);

        // --- init slab to (0,0): 4000 uint4 stores ---
        uint4* g4 = (uint4*)grid;
        const uint4 z4 = make_uint4(0u, 0u, 0u, 0u);
        for (int c = tid; c < CELLS / 2; c += 1024)
            g4[c] = z4;
        __syncthreads();

        // --- scatter: lazy predicated value load (each voxel hits ONE pass) ---
        #pragma unroll
        for (int it = 0; it < 32; ++it) {
            const unsigned cell = (cpk[it >> 1] >> ((it & 1) << 4)) & 0xFFFFu;
            const unsigned rel  = cell - lo;       // wraps if below lo
            if (rel < (unsigned)CELLS) {
                const int v = tid + (it << 10);
                if (USE_PRE) {
                    grid[rel] = pre[v];            // L2-resident 8B load
                } else {
                    grid[rel] = make_float2(1.f / (1.f + expf(-ab[v])),
                                            1.f / (1.f + expf(-at[v])));
                }
                // dup cells: racy 8B write = unspecified winner (JAX set)
            }
        }
        __syncthreads();

        // --- march slab: rays tid and tid+1024 ---
        #pragma unroll
        for (int zl = 0; zl < DEPTH; ++zl) {
            const int base = zl * NRAYS;
            const float2 p0 = grid[base + tid];
            S0 = fmaf(T0 * p0.y, p0.x, S0);
            T0 *= (1.f - p0.y);
            if (has1) {
                const float2 p1 = grid[base + ray1];
                S1 = fmaf(T1 * p1.y, p1.x, S1);
                T1 *= (1.f - p1.y);
            }
        }
        __syncthreads();   // protect slab before next pass's init
    }

    out[b * NRAYS + tid] = S0;
    if (has1) out[b * NRAYS + ray1] = S1;
}

extern "C" void kernel_launch(void* const* d_in, const int* in_sizes, int n_in,
                              void* d_out, int out_size, void* d_ws, size_t ws_size,
                              hipStream_t stream)
{
    const float* Rall = (const float*)d_in[0];   // [512,3,3]
    const float* ab   = (const float*)d_in[1];   // [32,32,32,1]
    const float* at   = (const float*)d_in[2];   // [32,32,32,1]
    float*       out  = (float*)d_out;           // [512,40,40,1]
    float2*      pre  = (float2*)d_ws;

    const bool use_pre = ws_size >= (size_t)NVOX * sizeof(float2);

    if (use_pre) {
        prep_kernel<<<(NVOX + 255) / 256, 256, 0, stream>>>(ab, at, pre);
        render_kernel<true ><<<NBATCH, 1024, CELLS * 8, stream>>>(Rall, pre, ab, at, out);
    } else {
        render_kernel<false><<<NBATCH, 1024, CELLS * 8, stream>>>(Rall, pre, ab, at, out);
    }
}